// Round 5
// baseline (287.512 us; speedup 1.0000x reference)
//
#include <hip/hip_runtime.h>
#include <type_traits>

typedef __bf16 bfrag __attribute__((ext_vector_type(8)));
typedef float f32x4 __attribute__((ext_vector_type(4)));
typedef float f32x16 __attribute__((ext_vector_type(16)));
typedef unsigned short us8 __attribute__((ext_vector_type(8)));
typedef unsigned int u32x2 __attribute__((ext_vector_type(2)));
typedef unsigned int u32x4 __attribute__((ext_vector_type(4)));

__device__ __forceinline__ float bf2f(unsigned short s) {
  unsigned u = ((unsigned)s) << 16;
  float f;
  __builtin_memcpy(&f, &u, 4);
  return f;
}
__device__ __forceinline__ unsigned short f2bf(float f) {
  unsigned u;
  __builtin_memcpy(&u, &f, 4);
  u += 0x7fffu + ((u >> 16) & 1u);
  return (unsigned short)(u >> 16);
}
__device__ __forceinline__ float rdf(const void* p, size_t i, int isf) {
  return isf ? ((const float*)p)[i] : bf2f(((const unsigned short*)p)[i]);
}
__device__ __forceinline__ void gld16(const unsigned short* g, unsigned short* l) {
  __builtin_amdgcn_global_load_lds(
      (const __attribute__((address_space(1))) unsigned int*)g,
      (__attribute__((address_space(3))) unsigned int*)l, 16, 0, 0);
}
__device__ __forceinline__ unsigned cvtpk_bf16(float a, float b) {
  unsigned d;
  asm("v_cvt_pk_bf16_f32 %0, %1, %2" : "=v"(d) : "v"(a), "v"(b));
  return d;  // low16 = bf16(a), high16 = bf16(b)
}

// -------- layernorm unit: 4 tokens (1/wave) ----------------------------
template <int XMODE>
__device__ void norm_unit(const void* xin, const void* alpha, const void* beta,
                          unsigned short* out, int isf, int u) {
  constexpr int E = 512;
  int xf = XMODE ? 1 : isf;
  int tid = threadIdx.x;
  int wave = tid >> 6, lane = tid & 63;
  size_t tok = (size_t)u * 4 + wave;
  float v[8];
  if (xf) {
    const float* xp = (const float*)xin + tok * E + lane * 8;
    float4 a0 = *(const float4*)xp;
    float4 a1 = *(const float4*)(xp + 4);
    v[0] = a0.x; v[1] = a0.y; v[2] = a0.z; v[3] = a0.w;
    v[4] = a1.x; v[5] = a1.y; v[6] = a1.z; v[7] = a1.w;
  } else {
    us8 uu = *(const us8*)((const unsigned short*)xin + tok * E + lane * 8);
#pragma unroll
    for (int j = 0; j < 8; j++) v[j] = bf2f(uu[j]);
  }
  float s = 0.f, sq = 0.f;
#pragma unroll
  for (int j = 0; j < 8; j++) { s += v[j]; sq += v[j] * v[j]; }
#pragma unroll
  for (int off = 1; off < 64; off <<= 1) {
    s += __shfl_xor(s, off, 64);
    sq += __shfl_xor(sq, off, 64);
  }
  float mean = s * (1.0f / 512.0f);
  float var = fmaxf((sq - 512.0f * mean * mean) * (1.0f / 511.0f), 0.0f);
  float inv = rdf(alpha, 0, isf) / (sqrtf(var) + 1e-6f);
  float be = rdf(beta, 0, isf);
  us8 ov;
#pragma unroll
  for (int j = 0; j < 8; j++) ov[j] = f2bf((v[j] - mean) * inv + be);
  *(us8*)(out + tok * E + lane * 8) = ov;
}

// ---------------- setup: self-detect + weight transposes + bcat + norm1 --
__global__ __launch_bounds__(256) void setup_k(
    const unsigned short* __restrict__ x16,
    const void* wq, const void* wk, const void* wv, const void* wo,
    const void* w1, const void* w2,
    unsigned short* wqkvT, unsigned short* woT,
    unsigned short* w1T, unsigned short* w2T,
    const void* bq, const void* bk, const void* bv, const void* bo,
    const void* b1, const void* b2, float* __restrict__ bcat,
    const void* alpha1, const void* beta1, unsigned short* __restrict__ n1,
    int* __restrict__ flag) {
  __shared__ unsigned short tile[32][33];
  __shared__ int s_cnt;
  int tid = threadIdx.x;
  int bid = blockIdx.x;
  if (tid == 0) s_cnt = 0;
  __syncthreads();
  {
    int c = 0;
    for (int i = tid; i < 4096; i += 256) {
      unsigned short s = x16[2 * i];
      int e = (s >> 7) & 0xFF;
      if (e > 0xC2 || (e != 0 && e < 0x3D)) c++;
    }
    atomicAdd(&s_cnt, c);
  }
  __syncthreads();
  const int isf = (s_cnt > 256) ? 1 : 0;
  if (bid == 0 && tid == 0) flag[0] = isf;

  if (bid >= 3090) {  // norm1
    norm_unit<0>(x16, alpha1, beta1, n1, isf, bid - 3090);
    return;
  }
  if (bid >= 3072) {  // bias concat
    int i = (bid - 3072) * 256 + tid;
    if (i < 4608) {
      float v;
      if (i < 512) v = rdf(bq, i, isf);
      else if (i < 1024) v = rdf(bk, i - 512, isf);
      else if (i < 1536) v = rdf(bv, i - 1024, isf);
      else if (i < 2048) v = rdf(bo, i - 1536, isf);
      else if (i < 4096) v = rdf(b1, i - 2048, isf);
      else v = rdf(b2, i - 4096, isf);
      bcat[i] = v;
    }
    return;
  }
  const void* W;
  unsigned short* Wt;
  int K, N, t;
  if (bid < 1024) {
    K = 512; N = 512; t = bid & 255;
    if (bid < 256) { W = wq; Wt = wqkvT; }
    else if (bid < 512) { W = wk; Wt = wqkvT + 262144; }
    else if (bid < 768) { W = wv; Wt = wqkvT + 524288; }
    else { W = wo; Wt = woT; }
  } else if (bid < 2048) {
    W = w1; Wt = w1T; K = 512; N = 2048; t = bid - 1024;
  } else {
    W = w2; Wt = w2T; K = 2048; N = 512; t = bid - 2048;
  }
  int nx = N >> 5;
  int n0 = (t % nx) * 32, k0 = (t / nx) * 32;
#pragma unroll
  for (int i = 0; i < 4; i++) {
    int e = tid + i * 256;
    int r = e >> 5, c = e & 31;
    tile[r][c] = f2bf(rdf(W, (size_t)(k0 + r) * N + n0 + c, isf));
  }
  __syncthreads();
#pragma unroll
  for (int i = 0; i < 4; i++) {
    int e = tid + i * 256;
    int r = e >> 5, c = e & 31;
    Wt[(size_t)(n0 + r) * K + k0 + c] = tile[c][r];
  }
}

// ---------------- V transpose: qkb v-cols -> vbt[bh][d][s] --------------
__global__ __launch_bounds__(256) void vtrans_k(
    const unsigned short* __restrict__ qkb, unsigned short* __restrict__ vbt) {
  __shared__ unsigned short tile[32][33];
  int tid = threadIdx.x;
  int u = blockIdx.x;
  int s0 = (u & 63) * 32;
  int d0 = ((u >> 6) & 1) * 32;
  int bh = u >> 7, b = bh >> 3, h = bh & 7;
#pragma unroll
  for (int i = 0; i < 4; i++) {
    int e = tid + i * 256;
    int r = e >> 5, c = e & 31;
    tile[r][c] = qkb[((size_t)b * 2048 + s0 + r) * 1536 + 1024 + h * 64 + d0 + c];
  }
  __syncthreads();
#pragma unroll
  for (int i = 0; i < 4; i++) {
    int e = tid + i * 256;
    int r = e >> 5, c = e & 31;
    vbt[((size_t)bh * 64 + d0 + r) * 2048 + s0 + c] = tile[c][r];
  }
}

// ---------------- norm2 standalone (x1 f32 -> n2 bf16) ------------------
__global__ __launch_bounds__(256) void norm2_k(
    const void* __restrict__ xin, const void* __restrict__ alpha,
    const void* __restrict__ beta, unsigned short* __restrict__ out,
    const int* __restrict__ flag) {
  norm_unit<1>(xin, alpha, beta, out, flag[0], blockIdx.x);
}

// ---------------- GEMM: 128xTN tile, BK=64, XOR-swizzled LDS ------------
template <int TN, int RES, int OUTM, int RELU>
__global__ __launch_bounds__(256, 3) void gemm2_k(
    const unsigned short* __restrict__ A,
    const unsigned short* __restrict__ Bt,
    const float* __restrict__ bias,
    const void* __restrict__ res,
    void* __restrict__ outp,
    int N, int K, const int* __restrict__ flag) {
  constexpr int MT = (TN == 128) ? 4 : 2;
  constexpr int BROWS = TN / 4;  // Bs rows staged per wave
  __shared__ alignas(16) unsigned short As[128 * 64];  // 16 KB
  __shared__ alignas(16) unsigned short Bs[TN * 64];   // 16/8 KB
  int isf = flag[0];
  int outf32 = (OUTM == 1) || (OUTM == 2 && isf);
  int tid = threadIdx.x;
  int wave = tid >> 6, lane = tid & 63;
  int quad = lane >> 4, l16 = lane & 15, l7 = l16 & 7;
  int wm = (TN == 128) ? (wave >> 1) : wave;
  int wn = (TN == 128) ? (wave & 1) : 0;
  size_t m0 = (size_t)blockIdx.x * 128;
  size_t n0 = (size_t)blockIdx.y * TN;

  int lrow = lane >> 3;                 // 0..7
  int gcol = 8 * ((lane & 7) ^ lrow);   // swizzled source chunk (shorts)

  const unsigned short* ag = A + (m0 + wave * 32 + lrow) * K + gcol;
  const unsigned short* bg = Bt + (n0 + wave * BROWS + lrow) * K + gcol;
  unsigned short* asl = &As[(wave * 32) * 64];
  unsigned short* bsl = &Bs[(wave * BROWS) * 64];

  f32x4 acc[MT][4];
#pragma unroll
  for (int i = 0; i < MT; i++)
#pragma unroll
    for (int j = 0; j < 4; j++) acc[i][j] = {0.f, 0.f, 0.f, 0.f};

  for (int k0 = 0; k0 < K; k0 += 64) {
    __syncthreads();
#pragma unroll
    for (int c = 0; c < 4; c++)
      gld16(ag + (size_t)(8 * c) * K + k0, asl + (8 * c) * 64);
#pragma unroll
    for (int c = 0; c < BROWS / 8; c++)
      gld16(bg + (size_t)(8 * c) * K + k0, bsl + (8 * c) * 64);
    __syncthreads();
#pragma unroll
    for (int ko = 0; ko < 2; ko++) {
      int slot = ((4 * ko + quad) ^ l7) * 8;
      bfrag af[MT], bf[4];
#pragma unroll
      for (int i = 0; i < MT; i++)
        af[i] = *(const bfrag*)&As[(wm * (MT * 16) + i * 16 + l16) * 64 + slot];
#pragma unroll
      for (int j = 0; j < 4; j++)
        bf[j] = *(const bfrag*)&Bs[(wn * 64 + j * 16 + l16) * 64 + slot];
#pragma unroll
      for (int i = 0; i < MT; i++)
#pragma unroll
        for (int j = 0; j < 4; j++)
          acc[i][j] = __builtin_amdgcn_mfma_f32_16x16x32_bf16(af[i], bf[j], acc[i][j], 0, 0, 0);
    }
  }
#pragma unroll
  for (int j = 0; j < 4; j++) {
    size_t n = n0 + wn * 64 + j * 16 + l16;
    float bv = bias[n];
#pragma unroll
    for (int i = 0; i < MT; i++) {
#pragma unroll
      for (int r = 0; r < 4; r++) {
        size_t m = m0 + wm * (MT * 16) + i * 16 + quad * 4 + r;
        float vv = acc[i][j][r] + bv;
        if (RELU) vv = fmaxf(vv, 0.0f);
        if (RES == 1) vv += rdf(res, m * N + n, isf);
        else if (RES == 2) vv += ((const float*)res)[m * N + n];
        if (outf32) ((float*)outp)[m * N + n] = vv;
        else ((unsigned short*)outp)[m * N + n] = f2bf(vv);
      }
    }
  }
}

// ---------------- flash attention: intra-block key-split, 8 waves -------
// 512 blocks (XCD-chunked as before), 512 threads. Waves 0-3 process keys
// [0,1024), waves 4-7 keys [1024,2048), over the SAME 128 q-rows (wave w
// and w+4 share q-sub-block wv=w&3). Doubles waves/SIMD 2->4 (the R2-R4
// structures were grid-limited at 2048 waves; dependency stalls were ~60%
// of cycles with nothing to overlap). Each half runs the proven KVBLK=64
// double-buffered pipeline; barriers are lockstep across both halves
// (equal work). No-max softmax => halves merge exactly: O=O0+O1, l=l0+l1,
// done through LDS at block end (merge buffer overlays dead K tiles).
// No setprio (R3: fence, hurt), no sched_group_barrier (R4: null).
__global__ __launch_bounds__(512, 4) void attn_k(
    const unsigned short* __restrict__ qkb,  // [8192][1536] q|k|v
    const unsigned short* __restrict__ vbt,  // [32*64][2048] = V^T per bh
    const int* __restrict__ mask,
    unsigned short* __restrict__ ctx) {      // [8192][512]
  constexpr int S = 2048;
  __shared__ alignas(16) unsigned short Kt[2][2][64 * 64];  // [kh][buf] 32 KB
  __shared__ alignas(16) unsigned short Vt[2][2][64 * 64];  // [kh][buf] 32 KB
  __shared__ alignas(16) float mskf[S];                     // 8 KB
  __shared__ float ml[2][128];
  __shared__ int s_all;
  int tid = threadIdx.x, wave = tid >> 6, lane = tid & 63;
  int kh = wave >> 2, wv = wave & 3;
  int l32 = lane & 31, hi = lane >> 5;

  // XCD-aware work mapping (512 blocks, 8 XCDs round-robin by linear id)
  int lin = blockIdx.x;
  int work = (lin & 7) * 64 + (lin >> 3);
  int bh = work >> 4;          // 0..31
  int q0 = (work & 15) * 128;  // 0..1920
  int b = bh >> 3, h = bh & 7;
  size_t rowbase = (size_t)b * S;
  const float SC = 0.18033688f;  // 0.125 * log2(e)

  // Q fragments (B-operand): col=q=l32, k(d) = 16*ds + 8*hi + j
  bfrag qf[4];
  {
    const unsigned short* qp =
        qkb + (rowbase + q0 + wv * 32 + l32) * 1536 + h * 64 + hi * 8;
#pragma unroll
    for (int ds = 0; ds < 4; ds++) qf[ds] = *(const bfrag*)(qp + ds * 16);
  }

  int srow_l = lane >> 3;  // 0..7; equals (staged row)&7 -> swizzle const/lane
  int sc = lane & 7;
  int swz = (sc ^ srow_l) * 8;
  const unsigned short* kgb = qkb + 512 + h * 64;
  const unsigned short* vgb = vbt + (size_t)bh * 64 * S;

  // staging pointers (strength-reduced); each wave stages 16 rows of its
  // half's K and V tiles
  const unsigned short* kp[2];
  const unsigned short* vp[2];
#pragma unroll
  for (int i = 0; i < 2; i++) {
    int r = wv * 16 + i * 8 + srow_l;
    kp[i] = kgb + (rowbase + kh * 1024 + r) * 1536 + swz;
    vp[i] = vgb + (size_t)r * S + kh * 1024 + swz;
  }

  auto STAGE = [&](int buf) {
#pragma unroll
    for (int i = 0; i < 2; i++) {
      gld16(kp[i], &Kt[kh][buf][(wv * 16 + i * 8) * 64]);
      kp[i] += 64 * 1536;
      gld16(vp[i], &Vt[kh][buf][(wv * 16 + i * 8) * 64]);
      vp[i] += 64;
    }
  };

  f32x16 o[2];
#pragma unroll
  for (int i = 0; i < 16; i++) { o[0][i] = 0.f; o[1][i] = 0.f; }
  f32x16 z16;
#pragma unroll
  for (int i = 0; i < 16; i++) z16[i] = 0.f;
  float l_i = 0.f;

  STAGE(0);
  if (tid == 0) s_all = 1;
  __syncthreads();
  {
    int ok = 1;
    for (int i = tid; i < S; i += 512) {
      int mv = mask[rowbase + i];
      ok &= (mv != 0);
      mskf[i] = mv ? 0.0f : -1e5f;
    }
    atomicAnd(&s_all, ok);
  }
  __syncthreads();  // tile 0 + mask + s_all ready
  int am = s_all;

  auto BODY = [&](auto amc) {
    constexpr bool AM = decltype(amc)::value;
    for (int it = 0; it < 16; it++) {
      int cur = it & 1;
      if (it + 1 < 16) STAGE(cur ^ 1);  // in flight across whole compute

      // ---- QK^T (swapped): pacc[t] = D[key in tile t][q] ----
      f32x16 pacc[2];
#pragma unroll
      for (int t = 0; t < 2; t++) {
        int r = t * 32 + l32;
#pragma unroll
        for (int ds = 0; ds < 4; ds++) {
          int phys = ((2 * ds + hi) ^ (l32 & 7)) * 8;
          bfrag kf = *(const bfrag*)&Kt[kh][cur][r * 64 + phys];
          pacc[t] = __builtin_amdgcn_mfma_f32_32x32x16_bf16(
              kf, qf[ds], ds == 0 ? z16 : pacc[t], 0, 0, 0);
        }
      }

      // ---- softmax: key = (reg&3) + 8*(reg>>2) + 4*hi + 32*t, q=l32 ----
      unsigned pb[16];
#pragma unroll
      for (int t = 0; t < 2; t++) {
#pragma unroll
        for (int g = 0; g < 4; g++) {
          float p0, p1, p2, p3;
          if constexpr (AM) {
            p0 = __builtin_amdgcn_exp2f(pacc[t][g * 4 + 0] * SC);
            p1 = __builtin_amdgcn_exp2f(pacc[t][g * 4 + 1] * SC);
            p2 = __builtin_amdgcn_exp2f(pacc[t][g * 4 + 2] * SC);
            p3 = __builtin_amdgcn_exp2f(pacc[t][g * 4 + 3] * SC);
          } else {
            float4 m4 =
                *(const float4*)&mskf[kh * 1024 + it * 64 + t * 32 + g * 8 + hi * 4];
            p0 = __builtin_amdgcn_exp2f(fmaf(pacc[t][g * 4 + 0], SC, m4.x));
            p1 = __builtin_amdgcn_exp2f(fmaf(pacc[t][g * 4 + 1], SC, m4.y));
            p2 = __builtin_amdgcn_exp2f(fmaf(pacc[t][g * 4 + 2], SC, m4.z));
            p3 = __builtin_amdgcn_exp2f(fmaf(pacc[t][g * 4 + 3], SC, m4.w));
          }
          l_i += (p0 + p1) + (p2 + p3);
          pb[t * 8 + g * 2] = cvtpk_bf16(p0, p1);
          pb[t * 8 + g * 2 + 1] = cvtpk_bf16(p2, p3);
        }
      }

      // ---- PV: O[q][d] += P[q][key] * V^T[d][key] ----
#pragma unroll
      for (int ks = 0; ks < 4; ks++) {
        int t = ks >> 1, e = ks & 1;
        u32x2 sA = __builtin_amdgcn_permlane32_swap(
            pb[t * 8 + 4 * e + 0], pb[t * 8 + 4 * e + 2], false, false);
        u32x2 sB = __builtin_amdgcn_permlane32_swap(
            pb[t * 8 + 4 * e + 1], pb[t * 8 + 4 * e + 3], false, false);
        u32x4 pw = {sA.x, sB.x, sA.y, sB.y};
        bfrag pf = __builtin_bit_cast(bfrag, pw);
#pragma unroll
        for (int dt = 0; dt < 2; dt++) {
          int r = dt * 32 + l32;
          int phys = ((2 * ks + hi) ^ (l32 & 7)) * 8;
          bfrag vf = *(const bfrag*)&Vt[kh][cur][r * 64 + phys];
          o[dt] = __builtin_amdgcn_mfma_f32_32x32x16_bf16(pf, vf, o[dt], 0, 0, 0);
        }
      }
      __syncthreads();  // next tile staged + all reads of cur done
    }
  };
  if (am) BODY(std::integral_constant<bool, true>{});
  else    BODY(std::integral_constant<bool, false>{});

  // ---- merge halves through LDS, normalize, store ----
  // l: lane's partial covers its hi half-keys; swap+add -> per-q total
  {
    unsigned lu = __builtin_bit_cast(unsigned, l_i);
    u32x2 lr = __builtin_amdgcn_permlane32_swap(lu, lu, false, false);
    float l_tot = __builtin_bit_cast(float, lr.x) + __builtin_bit_cast(float, lr.y);
    if (lane < 32) ml[kh][wv * 32 + l32] = l_tot;
  }
  float* mrg = (float*)&Kt[0][0][0];  // 32 KB = 4*32*64 f32, K tiles dead
  if (kh == 1) {
#pragma unroll
    for (int dt = 0; dt < 2; dt++) {
#pragma unroll
      for (int reg = 0; reg < 16; reg++) {
        int ql = (reg & 3) + 8 * (reg >> 2) + 4 * hi;
        mrg[wv * 2048 + ql * 64 + dt * 32 + l32] = o[dt][reg];
      }
    }
  }
  __syncthreads();
  if (kh == 0) {
#pragma unroll
    for (int dt = 0; dt < 2; dt++) {
#pragma unroll
      for (int reg = 0; reg < 16; reg++) {
        int ql = (reg & 3) + 8 * (reg >> 2) + 4 * hi;
        float inv = 1.0f / fmaxf(ml[0][wv * 32 + ql] + ml[1][wv * 32 + ql], 1e-30f);
        float val = (o[dt][reg] + mrg[wv * 2048 + ql * 64 + dt * 32 + l32]) * inv;
        size_t qrow = rowbase + q0 + wv * 32 + ql;
        ctx[qrow * 512 + h * 64 + dt * 32 + l32] = f2bf(val);
      }
    }
  }
}

extern "C" void kernel_launch(void* const* d_in, const int* in_sizes, int n_in,
                              void* d_out, int out_size, void* d_ws, size_t ws_size,
                              hipStream_t stream) {
  const unsigned short* x = (const unsigned short*)d_in[0];
  const int* mask         = (const int*)d_in[1];
  const void* wq = d_in[2];  const void* bq = d_in[3];
  const void* wk = d_in[4];  const void* bk = d_in[5];
  const void* wv = d_in[6];  const void* bv = d_in[7];
  const void* wo = d_in[8];  const void* bo = d_in[9];
  const void* w1 = d_in[10]; const void* b1 = d_in[11];
  const void* w2 = d_in[12]; const void* b2 = d_in[13];
  const void* alpha1 = d_in[14]; const void* beta1 = d_in[15];
  const void* alpha2 = d_in[16]; const void* beta2 = d_in[17];

  char* ws = (char*)d_ws;
  int* flag            = (int*)(ws + 0);
  unsigned short* wqkvT= (unsigned short*)(ws + 65536);    // [1536][512]
  unsigned short* woT  = (unsigned short*)(ws + 1638400);
  unsigned short* w1T  = (unsigned short*)(ws + 2162688);  // [2048][512]
  unsigned short* w2T  = (unsigned short*)(ws + 4259840);  // [512][2048]
  float*          bcat = (float*)         (ws + 6356992);  // 4608 f32
  float*          x1   = (float*)         (ws + 6422528);  // [8192][512] f32
  unsigned short* n1   = (unsigned short*)(ws + 23199744); // also ctx, n2
  unsigned short* qkb  = (unsigned short*)(ws + 31588352); // [8192][1536]
  unsigned short* vbt  = (unsigned short*)(ws + 56754176); // [2048][2048]
  unsigned short* ff1  = qkb;                              // [8192][2048] overlay

  dim3 blk(256);

  setup_k<<<5138, blk, 0, stream>>>(x, wq, wk, wv, wo, w1, w2,
                                    wqkvT, woT, w1T, w2T,
                                    bq, bk, bv, bo, b1, b2, bcat,
                                    alpha1, beta1, n1, flag);
  // fused QKV: [8192][512] @ [1536][512]^T -> qkb
  gemm2_k<128, 0, 0, 0><<<dim3(64, 12), blk, 0, stream>>>(n1, wqkvT, bcat, nullptr, qkb, 1536, 512, flag);
  vtrans_k<<<4096, blk, 0, stream>>>(qkb, vbt);
  attn_k<<<512, dim3(512), 0, stream>>>(qkb, vbt, mask, n1);
  // out projection + residual(x) -> x1 f32
  gemm2_k<64, 1, 1, 0><<<dim3(64, 8), blk, 0, stream>>>(n1, woT, bcat + 1536, (const void*)x, x1, 512, 512, flag);
  norm2_k<<<2048, blk, 0, stream>>>(x1, alpha2, beta2, n1, flag);
  // ffn1 + relu -> ff1
  gemm2_k<128, 0, 0, 1><<<dim3(64, 16), blk, 0, stream>>>(n1, w1T, bcat + 2048, nullptr, ff1, 2048, 512, flag);
  // ffn2 + residual(x1) -> d_out
  gemm2_k<64, 2, 2, 0><<<dim3(64, 8), blk, 0, stream>>>(ff1, w2T, bcat + 4096, x1, d_out, 512, 2048, flag);
}

// Round 6
// 286.930 us; speedup vs baseline: 1.0020x; 1.0020x over previous
//
#include <hip/hip_runtime.h>
#include <type_traits>

typedef __bf16 bfrag __attribute__((ext_vector_type(8)));
typedef float f32x4 __attribute__((ext_vector_type(4)));
typedef float f32x16 __attribute__((ext_vector_type(16)));
typedef unsigned short us8 __attribute__((ext_vector_type(8)));
typedef unsigned int u32x2 __attribute__((ext_vector_type(2)));
typedef unsigned int u32x4 __attribute__((ext_vector_type(4)));

__device__ __forceinline__ float bf2f(unsigned short s) {
  unsigned u = ((unsigned)s) << 16;
  float f;
  __builtin_memcpy(&f, &u, 4);
  return f;
}
__device__ __forceinline__ unsigned short f2bf(float f) {
  unsigned u;
  __builtin_memcpy(&u, &f, 4);
  u += 0x7fffu + ((u >> 16) & 1u);
  return (unsigned short)(u >> 16);
}
__device__ __forceinline__ float rdf(const void* p, size_t i, int isf) {
  return isf ? ((const float*)p)[i] : bf2f(((const unsigned short*)p)[i]);
}
__device__ __forceinline__ void gld16(const unsigned short* g, unsigned short* l) {
  __builtin_amdgcn_global_load_lds(
      (const __attribute__((address_space(1))) unsigned int*)g,
      (__attribute__((address_space(3))) unsigned int*)l, 16, 0, 0);
}
__device__ __forceinline__ unsigned cvtpk_bf16(float a, float b) {
  unsigned d;
  asm("v_cvt_pk_bf16_f32 %0, %1, %2" : "=v"(d) : "v"(a), "v"(b));
  return d;  // low16 = bf16(a), high16 = bf16(b)
}

// -------- layernorm unit: 4 tokens (1/wave) ----------------------------
template <int XMODE>
__device__ void norm_unit(const void* xin, const void* alpha, const void* beta,
                          unsigned short* out, int isf, int u) {
  constexpr int E = 512;
  int xf = XMODE ? 1 : isf;
  int tid = threadIdx.x;
  int wave = tid >> 6, lane = tid & 63;
  size_t tok = (size_t)u * 4 + wave;
  float v[8];
  if (xf) {
    const float* xp = (const float*)xin + tok * E + lane * 8;
    float4 a0 = *(const float4*)xp;
    float4 a1 = *(const float4*)(xp + 4);
    v[0] = a0.x; v[1] = a0.y; v[2] = a0.z; v[3] = a0.w;
    v[4] = a1.x; v[5] = a1.y; v[6] = a1.z; v[7] = a1.w;
  } else {
    us8 uu = *(const us8*)((const unsigned short*)xin + tok * E + lane * 8);
#pragma unroll
    for (int j = 0; j < 8; j++) v[j] = bf2f(uu[j]);
  }
  float s = 0.f, sq = 0.f;
#pragma unroll
  for (int j = 0; j < 8; j++) { s += v[j]; sq += v[j] * v[j]; }
#pragma unroll
  for (int off = 1; off < 64; off <<= 1) {
    s += __shfl_xor(s, off, 64);
    sq += __shfl_xor(sq, off, 64);
  }
  float mean = s * (1.0f / 512.0f);
  float var = fmaxf((sq - 512.0f * mean * mean) * (1.0f / 511.0f), 0.0f);
  float inv = rdf(alpha, 0, isf) / (sqrtf(var) + 1e-6f);
  float be = rdf(beta, 0, isf);
  us8 ov;
#pragma unroll
  for (int j = 0; j < 8; j++) ov[j] = f2bf((v[j] - mean) * inv + be);
  *(us8*)(out + tok * E + lane * 8) = ov;
}

// ---------------- setup: self-detect + weight transposes + bcat + norm1 --
__global__ __launch_bounds__(256) void setup_k(
    const unsigned short* __restrict__ x16,
    const void* wq, const void* wk, const void* wv, const void* wo,
    const void* w1, const void* w2,
    unsigned short* wqkvT, unsigned short* woT,
    unsigned short* w1T, unsigned short* w2T,
    const void* bq, const void* bk, const void* bv, const void* bo,
    const void* b1, const void* b2, float* __restrict__ bcat,
    const void* alpha1, const void* beta1, unsigned short* __restrict__ n1,
    int* __restrict__ flag) {
  __shared__ unsigned short tile[32][33];
  __shared__ int s_cnt;
  int tid = threadIdx.x;
  int bid = blockIdx.x;
  if (tid == 0) s_cnt = 0;
  __syncthreads();
  {
    int c = 0;
    for (int i = tid; i < 4096; i += 256) {
      unsigned short s = x16[2 * i];
      int e = (s >> 7) & 0xFF;
      if (e > 0xC2 || (e != 0 && e < 0x3D)) c++;
    }
    atomicAdd(&s_cnt, c);
  }
  __syncthreads();
  const int isf = (s_cnt > 256) ? 1 : 0;
  if (bid == 0 && tid == 0) flag[0] = isf;

  if (bid >= 3090) {  // norm1
    norm_unit<0>(x16, alpha1, beta1, n1, isf, bid - 3090);
    return;
  }
  if (bid >= 3072) {  // bias concat
    int i = (bid - 3072) * 256 + tid;
    if (i < 4608) {
      float v;
      if (i < 512) v = rdf(bq, i, isf);
      else if (i < 1024) v = rdf(bk, i - 512, isf);
      else if (i < 1536) v = rdf(bv, i - 1024, isf);
      else if (i < 2048) v = rdf(bo, i - 1536, isf);
      else if (i < 4096) v = rdf(b1, i - 2048, isf);
      else v = rdf(b2, i - 4096, isf);
      bcat[i] = v;
    }
    return;
  }
  const void* W;
  unsigned short* Wt;
  int K, N, t;
  if (bid < 1024) {
    K = 512; N = 512; t = bid & 255;
    if (bid < 256) { W = wq; Wt = wqkvT; }
    else if (bid < 512) { W = wk; Wt = wqkvT + 262144; }
    else if (bid < 768) { W = wv; Wt = wqkvT + 524288; }
    else { W = wo; Wt = woT; }
  } else if (bid < 2048) {
    W = w1; Wt = w1T; K = 512; N = 2048; t = bid - 1024;
  } else {
    W = w2; Wt = w2T; K = 2048; N = 512; t = bid - 2048;
  }
  int nx = N >> 5;
  int n0 = (t % nx) * 32, k0 = (t / nx) * 32;
#pragma unroll
  for (int i = 0; i < 4; i++) {
    int e = tid + i * 256;
    int r = e >> 5, c = e & 31;
    tile[r][c] = f2bf(rdf(W, (size_t)(k0 + r) * N + n0 + c, isf));
  }
  __syncthreads();
#pragma unroll
  for (int i = 0; i < 4; i++) {
    int e = tid + i * 256;
    int r = e >> 5, c = e & 31;
    Wt[(size_t)(n0 + r) * K + k0 + c] = tile[c][r];
  }
}

// ---------------- V transpose: qkb v-cols -> vbt[bh][d][s] --------------
__global__ __launch_bounds__(256) void vtrans_k(
    const unsigned short* __restrict__ qkb, unsigned short* __restrict__ vbt) {
  __shared__ unsigned short tile[32][33];
  int tid = threadIdx.x;
  int u = blockIdx.x;
  int s0 = (u & 63) * 32;
  int d0 = ((u >> 6) & 1) * 32;
  int bh = u >> 7, b = bh >> 3, h = bh & 7;
#pragma unroll
  for (int i = 0; i < 4; i++) {
    int e = tid + i * 256;
    int r = e >> 5, c = e & 31;
    tile[r][c] = qkb[((size_t)b * 2048 + s0 + r) * 1536 + 1024 + h * 64 + d0 + c];
  }
  __syncthreads();
#pragma unroll
  for (int i = 0; i < 4; i++) {
    int e = tid + i * 256;
    int r = e >> 5, c = e & 31;
    vbt[((size_t)bh * 64 + d0 + r) * 2048 + s0 + c] = tile[c][r];
  }
}

// ---------------- norm2 standalone (x1 f32 -> n2 bf16) ------------------
__global__ __launch_bounds__(256) void norm2_k(
    const void* __restrict__ xin, const void* __restrict__ alpha,
    const void* __restrict__ beta, unsigned short* __restrict__ out,
    const int* __restrict__ flag) {
  norm_unit<1>(xin, alpha, beta, out, flag[0], blockIdx.x);
}

// ---------------- GEMM: 128xTN tile, BK=64, XOR-swizzled LDS ------------
template <int TN, int RES, int OUTM, int RELU>
__global__ __launch_bounds__(256, 3) void gemm2_k(
    const unsigned short* __restrict__ A,
    const unsigned short* __restrict__ Bt,
    const float* __restrict__ bias,
    const void* __restrict__ res,
    void* __restrict__ outp,
    int N, int K, const int* __restrict__ flag) {
  constexpr int MT = (TN == 128) ? 4 : 2;
  constexpr int BROWS = TN / 4;  // Bs rows staged per wave
  __shared__ alignas(16) unsigned short As[128 * 64];  // 16 KB
  __shared__ alignas(16) unsigned short Bs[TN * 64];   // 16/8 KB
  int isf = flag[0];
  int outf32 = (OUTM == 1) || (OUTM == 2 && isf);
  int tid = threadIdx.x;
  int wave = tid >> 6, lane = tid & 63;
  int quad = lane >> 4, l16 = lane & 15, l7 = l16 & 7;
  int wm = (TN == 128) ? (wave >> 1) : wave;
  int wn = (TN == 128) ? (wave & 1) : 0;
  size_t m0 = (size_t)blockIdx.x * 128;
  size_t n0 = (size_t)blockIdx.y * TN;

  int lrow = lane >> 3;                 // 0..7
  int gcol = 8 * ((lane & 7) ^ lrow);   // swizzled source chunk (shorts)

  const unsigned short* ag = A + (m0 + wave * 32 + lrow) * K + gcol;
  const unsigned short* bg = Bt + (n0 + wave * BROWS + lrow) * K + gcol;
  unsigned short* asl = &As[(wave * 32) * 64];
  unsigned short* bsl = &Bs[(wave * BROWS) * 64];

  f32x4 acc[MT][4];
#pragma unroll
  for (int i = 0; i < MT; i++)
#pragma unroll
    for (int j = 0; j < 4; j++) acc[i][j] = {0.f, 0.f, 0.f, 0.f};

  for (int k0 = 0; k0 < K; k0 += 64) {
    __syncthreads();
#pragma unroll
    for (int c = 0; c < 4; c++)
      gld16(ag + (size_t)(8 * c) * K + k0, asl + (8 * c) * 64);
#pragma unroll
    for (int c = 0; c < BROWS / 8; c++)
      gld16(bg + (size_t)(8 * c) * K + k0, bsl + (8 * c) * 64);
    __syncthreads();
#pragma unroll
    for (int ko = 0; ko < 2; ko++) {
      int slot = ((4 * ko + quad) ^ l7) * 8;
      bfrag af[MT], bf[4];
#pragma unroll
      for (int i = 0; i < MT; i++)
        af[i] = *(const bfrag*)&As[(wm * (MT * 16) + i * 16 + l16) * 64 + slot];
#pragma unroll
      for (int j = 0; j < 4; j++)
        bf[j] = *(const bfrag*)&Bs[(wn * 64 + j * 16 + l16) * 64 + slot];
#pragma unroll
      for (int i = 0; i < MT; i++)
#pragma unroll
        for (int j = 0; j < 4; j++)
          acc[i][j] = __builtin_amdgcn_mfma_f32_16x16x32_bf16(af[i], bf[j], acc[i][j], 0, 0, 0);
    }
  }
#pragma unroll
  for (int j = 0; j < 4; j++) {
    size_t n = n0 + wn * 64 + j * 16 + l16;
    float bv = bias[n];
#pragma unroll
    for (int i = 0; i < MT; i++) {
#pragma unroll
      for (int r = 0; r < 4; r++) {
        size_t m = m0 + wm * (MT * 16) + i * 16 + quad * 4 + r;
        float vv = acc[i][j][r] + bv;
        if (RELU) vv = fmaxf(vv, 0.0f);
        if (RES == 1) vv += rdf(res, m * N + n, isf);
        else if (RES == 2) vv += ((const float*)res)[m * N + n];
        if (outf32) ((float*)outp)[m * N + n] = vv;
        else ((unsigned short*)outp)[m * N + n] = f2bf(vv);
      }
    }
  }
}

// ---------------- flash attention: 64q/wave, key-split, 8 waves ---------
// R5 lesson: 2x occupancy = 0 gain; LDS pipe was ~66% busy (reads scale
// with wave count at fixed q/wave) and launch_bounds(512,4)'s 128-reg cap
// caused loop spills (WRITE_SIZE 8.2->15.4MB). This round: 64 q per wave
// (2 q-groups of 32) -> the same 16 ds_read_b128/iter serve 2x the work;
// per-CU ds_reads AND staging/gld16 writes halve. 256 blocks x 512 thr
// (4 q-subblocks x 2 key-halves), bounds(512,2) -> 256-reg cap, no spill.
// t-sequential pacc/pb keeps transient pressure low. Key-split merge via
// LDS (exact, no-max softmax). XCD chunking: 4 bh per XCD (2MB L2 set).
__global__ __launch_bounds__(512, 2) void attn_k(
    const unsigned short* __restrict__ qkb,  // [8192][1536] q|k|v
    const unsigned short* __restrict__ vbt,  // [32*64][2048] = V^T per bh
    const int* __restrict__ mask,
    unsigned short* __restrict__ ctx) {      // [8192][512]
  constexpr int S = 2048;
  __shared__ alignas(16) unsigned short Kt[2][2][64 * 64];  // [kh][buf] 32 KB
  __shared__ alignas(16) unsigned short Vt[2][2][64 * 64];  // [kh][buf] 32 KB
  __shared__ alignas(16) float mskf[S];                     // 8 KB
  __shared__ float ml[2][256];                              // 2 KB
  __shared__ int s_all;
  int tid = threadIdx.x, wave = tid >> 6, lane = tid & 63;
  int kh = wave >> 2, wv = wave & 3;
  int l32 = lane & 31, hi = lane >> 5;

  // XCD-aware work mapping (256 blocks, 8 XCDs round-robin by linear id)
  int lin = blockIdx.x;
  int work = (lin & 7) * 32 + (lin >> 3);
  int bh = work >> 3;          // 0..31 (4 consecutive bh per XCD)
  int q0 = (work & 7) * 256;   // 0..1792
  int b = bh >> 3, h = bh & 7;
  size_t rowbase = (size_t)b * S;
  const float SC = 0.18033688f;  // 0.125 * log2(e)

  // Q fragments (B-operand), 2 q-groups of 32: col=q=l32, k(d)=16ds+8hi+j
  bfrag qf[2][4];
#pragma unroll
  for (int qg = 0; qg < 2; qg++) {
    const unsigned short* qp =
        qkb + (rowbase + q0 + wv * 64 + qg * 32 + l32) * 1536 + h * 64 + hi * 8;
#pragma unroll
    for (int ds = 0; ds < 4; ds++) qf[qg][ds] = *(const bfrag*)(qp + ds * 16);
  }

  int srow_l = lane >> 3;  // 0..7; equals (staged row)&7 -> swizzle const/lane
  int sc = lane & 7;
  int swz = (sc ^ srow_l) * 8;
  const unsigned short* kgb = qkb + 512 + h * 64;
  const unsigned short* vgb = vbt + (size_t)bh * 64 * S;

  // staging pointers (strength-reduced); wave stages 16 rows of its half
  const unsigned short* kp[2];
  const unsigned short* vp[2];
#pragma unroll
  for (int i = 0; i < 2; i++) {
    int r = wv * 16 + i * 8 + srow_l;
    kp[i] = kgb + (rowbase + kh * 1024 + r) * 1536 + swz;
    vp[i] = vgb + (size_t)r * S + kh * 1024 + swz;
  }

  auto STAGE = [&](int buf) {
#pragma unroll
    for (int i = 0; i < 2; i++) {
      gld16(kp[i], &Kt[kh][buf][(wv * 16 + i * 8) * 64]);
      kp[i] += 64 * 1536;
      gld16(vp[i], &Vt[kh][buf][(wv * 16 + i * 8) * 64]);
      vp[i] += 64;
    }
  };

  f32x16 o[4];  // [qg*2+dt]
#pragma unroll
  for (int i = 0; i < 4; i++)
#pragma unroll
    for (int j = 0; j < 16; j++) o[i][j] = 0.f;
  float l_i[2] = {0.f, 0.f};

  STAGE(0);
  if (tid == 0) s_all = 1;
  __syncthreads();
  {
    int ok = 1;
    for (int i = tid; i < S; i += 512) {
      int mv = mask[rowbase + i];
      ok &= (mv != 0);
      mskf[i] = mv ? 0.0f : -1e5f;
    }
    atomicAnd(&s_all, ok);
  }
  __syncthreads();  // tile 0 + mask + s_all ready
  int am = s_all;

  auto BODY = [&](auto amc) {
    constexpr bool AM = decltype(amc)::value;
    for (int it = 0; it < 16; it++) {
      int cur = it & 1;
      if (it + 1 < 16) STAGE(cur ^ 1);  // in flight across whole compute

#pragma unroll
      for (int qg = 0; qg < 2; qg++) {
#pragma unroll
        for (int t = 0; t < 2; t++) {
          // ---- QK^T (swapped): pacc = D[key in sub-tile t][q] ----
          f32x16 pacc;
          {
            int r = t * 32 + l32;
            f32x16 z = {};
#pragma unroll
            for (int ds = 0; ds < 4; ds++) {
              int phys = ((2 * ds + hi) ^ (l32 & 7)) * 8;
              bfrag kf = *(const bfrag*)&Kt[kh][cur][r * 64 + phys];
              pacc = __builtin_amdgcn_mfma_f32_32x32x16_bf16(
                  kf, qf[qg][ds], ds == 0 ? z : pacc, 0, 0, 0);
            }
          }
          // ---- softmax: key = (reg&3)+8*(reg>>2)+4*hi+32*t, q=l32 ----
          unsigned pb[8];
#pragma unroll
          for (int g = 0; g < 4; g++) {
            float p0, p1, p2, p3;
            if constexpr (AM) {
              p0 = __builtin_amdgcn_exp2f(pacc[g * 4 + 0] * SC);
              p1 = __builtin_amdgcn_exp2f(pacc[g * 4 + 1] * SC);
              p2 = __builtin_amdgcn_exp2f(pacc[g * 4 + 2] * SC);
              p3 = __builtin_amdgcn_exp2f(pacc[g * 4 + 3] * SC);
            } else {
              float4 m4 =
                  *(const float4*)&mskf[kh * 1024 + it * 64 + t * 32 + g * 8 + hi * 4];
              p0 = __builtin_amdgcn_exp2f(fmaf(pacc[g * 4 + 0], SC, m4.x));
              p1 = __builtin_amdgcn_exp2f(fmaf(pacc[g * 4 + 1], SC, m4.y));
              p2 = __builtin_amdgcn_exp2f(fmaf(pacc[g * 4 + 2], SC, m4.z));
              p3 = __builtin_amdgcn_exp2f(fmaf(pacc[g * 4 + 3], SC, m4.w));
            }
            l_i[qg] += (p0 + p1) + (p2 + p3);
            pb[g * 2] = cvtpk_bf16(p0, p1);
            pb[g * 2 + 1] = cvtpk_bf16(p2, p3);
          }
          // ---- PV for this sub-tile: ks = 2t+e ----
#pragma unroll
          for (int e = 0; e < 2; e++) {
            u32x2 sA = __builtin_amdgcn_permlane32_swap(
                pb[4 * e + 0], pb[4 * e + 2], false, false);
            u32x2 sB = __builtin_amdgcn_permlane32_swap(
                pb[4 * e + 1], pb[4 * e + 3], false, false);
            u32x4 pw = {sA.x, sB.x, sA.y, sB.y};
            bfrag pf = __builtin_bit_cast(bfrag, pw);
            int ks = 2 * t + e;
#pragma unroll
            for (int dt = 0; dt < 2; dt++) {
              int r = dt * 32 + l32;
              int phys = ((2 * ks + hi) ^ (l32 & 7)) * 8;
              bfrag vf = *(const bfrag*)&Vt[kh][cur][r * 64 + phys];
              o[qg * 2 + dt] = __builtin_amdgcn_mfma_f32_32x32x16_bf16(
                  pf, vf, o[qg * 2 + dt], 0, 0, 0);
            }
          }
        }
      }
      __syncthreads();  // next tile staged + all reads of cur done
    }
  };
  if (am) BODY(std::integral_constant<bool, true>{});
  else    BODY(std::integral_constant<bool, false>{});

  // ---- merge halves through LDS, normalize, store ----
#pragma unroll
  for (int qg = 0; qg < 2; qg++) {
    unsigned lu = __builtin_bit_cast(unsigned, l_i[qg]);
    u32x2 lr = __builtin_amdgcn_permlane32_swap(lu, lu, false, false);
    float l_tot = __builtin_bit_cast(float, lr.x) + __builtin_bit_cast(float, lr.y);
    if (lane < 32) ml[kh][wv * 64 + qg * 32 + l32] = l_tot;
  }
  float* mrgK = (float*)&Kt[0][0][0];  // 32 KB: 256q x 32d (dt=0), K dead
  float* mrgV = (float*)&Vt[0][0][0];  // 32 KB: 256q x 32d (dt=1), V dead
  if (kh == 1) {
#pragma unroll
    for (int qg = 0; qg < 2; qg++) {
#pragma unroll
      for (int reg = 0; reg < 16; reg++) {
        int ql = (reg & 3) + 8 * (reg >> 2) + 4 * hi;
        int qi = wv * 64 + qg * 32 + ql;
        mrgK[qi * 32 + l32] = o[qg * 2 + 0][reg];
        mrgV[qi * 32 + l32] = o[qg * 2 + 1][reg];
      }
    }
  }
  __syncthreads();
  if (kh == 0) {
#pragma unroll
    for (int qg = 0; qg < 2; qg++) {
#pragma unroll
      for (int reg = 0; reg < 16; reg++) {
        int ql = (reg & 3) + 8 * (reg >> 2) + 4 * hi;
        int qi = wv * 64 + qg * 32 + ql;
        float inv = 1.0f / fmaxf(ml[0][qi] + ml[1][qi], 1e-30f);
        size_t qrow = rowbase + q0 + qi;
        float v0 = (o[qg * 2 + 0][reg] + mrgK[qi * 32 + l32]) * inv;
        float v1 = (o[qg * 2 + 1][reg] + mrgV[qi * 32 + l32]) * inv;
        ctx[qrow * 512 + h * 64 + l32] = f2bf(v0);
        ctx[qrow * 512 + h * 64 + 32 + l32] = f2bf(v1);
      }
    }
  }
}

extern "C" void kernel_launch(void* const* d_in, const int* in_sizes, int n_in,
                              void* d_out, int out_size, void* d_ws, size_t ws_size,
                              hipStream_t stream) {
  const unsigned short* x = (const unsigned short*)d_in[0];
  const int* mask         = (const int*)d_in[1];
  const void* wq = d_in[2];  const void* bq = d_in[3];
  const void* wk = d_in[4];  const void* bk = d_in[5];
  const void* wv = d_in[6];  const void* bv = d_in[7];
  const void* wo = d_in[8];  const void* bo = d_in[9];
  const void* w1 = d_in[10]; const void* b1 = d_in[11];
  const void* w2 = d_in[12]; const void* b2 = d_in[13];
  const void* alpha1 = d_in[14]; const void* beta1 = d_in[15];
  const void* alpha2 = d_in[16]; const void* beta2 = d_in[17];

  char* ws = (char*)d_ws;
  int* flag            = (int*)(ws + 0);
  unsigned short* wqkvT= (unsigned short*)(ws + 65536);    // [1536][512]
  unsigned short* woT  = (unsigned short*)(ws + 1638400);
  unsigned short* w1T  = (unsigned short*)(ws + 2162688);  // [2048][512]
  unsigned short* w2T  = (unsigned short*)(ws + 4259840);  // [512][2048]
  float*          bcat = (float*)         (ws + 6356992);  // 4608 f32
  float*          x1   = (float*)         (ws + 6422528);  // [8192][512] f32
  unsigned short* n1   = (unsigned short*)(ws + 23199744); // also ctx, n2
  unsigned short* qkb  = (unsigned short*)(ws + 31588352); // [8192][1536]
  unsigned short* vbt  = (unsigned short*)(ws + 56754176); // [2048][2048]
  unsigned short* ff1  = qkb;                              // [8192][2048] overlay

  dim3 blk(256);

  setup_k<<<5138, blk, 0, stream>>>(x, wq, wk, wv, wo, w1, w2,
                                    wqkvT, woT, w1T, w2T,
                                    bq, bk, bv, bo, b1, b2, bcat,
                                    alpha1, beta1, n1, flag);
  // fused QKV: [8192][512] @ [1536][512]^T -> qkb
  gemm2_k<128, 0, 0, 0><<<dim3(64, 12), blk, 0, stream>>>(n1, wqkvT, bcat, nullptr, qkb, 1536, 512, flag);
  vtrans_k<<<4096, blk, 0, stream>>>(qkb, vbt);
  attn_k<<<256, dim3(512), 0, stream>>>(qkb, vbt, mask, n1);
  // out projection + residual(x) -> x1 f32
  gemm2_k<64, 1, 1, 0><<<dim3(64, 8), blk, 0, stream>>>(n1, woT, bcat + 1536, (const void*)x, x1, 512, 512, flag);
  norm2_k<<<2048, blk, 0, stream>>>(x1, alpha2, beta2, n1, flag);
  // ffn1 + relu -> ff1
  gemm2_k<128, 0, 0, 1><<<dim3(64, 16), blk, 0, stream>>>(n1, w1T, bcat + 2048, nullptr, ff1, 2048, 512, flag);
  // ffn2 + residual(x1) -> d_out
  gemm2_k<64, 2, 2, 0><<<dim3(64, 8), blk, 0, stream>>>(ff1, w2T, bcat + 4096, x1, d_out, 512, 2048, flag);
}

// Round 7
// 264.953 us; speedup vs baseline: 1.0851x; 1.0829x over previous
//
#include <hip/hip_runtime.h>
#include <type_traits>

typedef __bf16 bfrag __attribute__((ext_vector_type(8)));
typedef float f32x4 __attribute__((ext_vector_type(4)));
typedef float f32x16 __attribute__((ext_vector_type(16)));
typedef unsigned short us8 __attribute__((ext_vector_type(8)));
typedef unsigned int u32x2 __attribute__((ext_vector_type(2)));
typedef unsigned int u32x4 __attribute__((ext_vector_type(4)));

__device__ __forceinline__ float bf2f(unsigned short s) {
  unsigned u = ((unsigned)s) << 16;
  float f;
  __builtin_memcpy(&f, &u, 4);
  return f;
}
__device__ __forceinline__ unsigned short f2bf(float f) {
  unsigned u;
  __builtin_memcpy(&u, &f, 4);
  u += 0x7fffu + ((u >> 16) & 1u);
  return (unsigned short)(u >> 16);
}
__device__ __forceinline__ float rdf(const void* p, size_t i, int isf) {
  return isf ? ((const float*)p)[i] : bf2f(((const unsigned short*)p)[i]);
}
__device__ __forceinline__ void gld16(const unsigned short* g, unsigned short* l) {
  __builtin_amdgcn_global_load_lds(
      (const __attribute__((address_space(1))) unsigned int*)g,
      (__attribute__((address_space(3))) unsigned int*)l, 16, 0, 0);
}
__device__ __forceinline__ unsigned cvtpk_bf16(float a, float b) {
  unsigned d;
  asm("v_cvt_pk_bf16_f32 %0, %1, %2" : "=v"(d) : "v"(a), "v"(b));
  return d;  // low16 = bf16(a), high16 = bf16(b)
}

// -------- layernorm unit: 4 tokens (1/wave) ----------------------------
template <int XMODE>
__device__ void norm_unit(const void* xin, const void* alpha, const void* beta,
                          unsigned short* out, int isf, int u) {
  constexpr int E = 512;
  int xf = XMODE ? 1 : isf;
  int tid = threadIdx.x;
  int wave = tid >> 6, lane = tid & 63;
  size_t tok = (size_t)u * 4 + wave;
  float v[8];
  if (xf) {
    const float* xp = (const float*)xin + tok * E + lane * 8;
    float4 a0 = *(const float4*)xp;
    float4 a1 = *(const float4*)(xp + 4);
    v[0] = a0.x; v[1] = a0.y; v[2] = a0.z; v[3] = a0.w;
    v[4] = a1.x; v[5] = a1.y; v[6] = a1.z; v[7] = a1.w;
  } else {
    us8 uu = *(const us8*)((const unsigned short*)xin + tok * E + lane * 8);
#pragma unroll
    for (int j = 0; j < 8; j++) v[j] = bf2f(uu[j]);
  }
  float s = 0.f, sq = 0.f;
#pragma unroll
  for (int j = 0; j < 8; j++) { s += v[j]; sq += v[j] * v[j]; }
#pragma unroll
  for (int off = 1; off < 64; off <<= 1) {
    s += __shfl_xor(s, off, 64);
    sq += __shfl_xor(sq, off, 64);
  }
  float mean = s * (1.0f / 512.0f);
  float var = fmaxf((sq - 512.0f * mean * mean) * (1.0f / 511.0f), 0.0f);
  float inv = rdf(alpha, 0, isf) / (sqrtf(var) + 1e-6f);
  float be = rdf(beta, 0, isf);
  us8 ov;
#pragma unroll
  for (int j = 0; j < 8; j++) ov[j] = f2bf((v[j] - mean) * inv + be);
  *(us8*)(out + tok * E + lane * 8) = ov;
}

// ---------------- setup: self-detect + weight transposes + bcat + norm1 --
__global__ __launch_bounds__(256) void setup_k(
    const unsigned short* __restrict__ x16,
    const void* wq, const void* wk, const void* wv, const void* wo,
    const void* w1, const void* w2,
    unsigned short* wqkvT, unsigned short* woT,
    unsigned short* w1T, unsigned short* w2T,
    const void* bq, const void* bk, const void* bv, const void* bo,
    const void* b1, const void* b2, float* __restrict__ bcat,
    const void* alpha1, const void* beta1, unsigned short* __restrict__ n1,
    int* __restrict__ flag) {
  __shared__ unsigned short tile[32][33];
  __shared__ int s_cnt;
  int tid = threadIdx.x;
  int bid = blockIdx.x;
  if (tid == 0) s_cnt = 0;
  __syncthreads();
  {
    int c = 0;
    for (int i = tid; i < 4096; i += 256) {
      unsigned short s = x16[2 * i];
      int e = (s >> 7) & 0xFF;
      if (e > 0xC2 || (e != 0 && e < 0x3D)) c++;
    }
    atomicAdd(&s_cnt, c);
  }
  __syncthreads();
  const int isf = (s_cnt > 256) ? 1 : 0;
  if (bid == 0 && tid == 0) flag[0] = isf;

  if (bid >= 3090) {  // norm1
    norm_unit<0>(x16, alpha1, beta1, n1, isf, bid - 3090);
    return;
  }
  if (bid >= 3072) {  // bias concat
    int i = (bid - 3072) * 256 + tid;
    if (i < 4608) {
      float v;
      if (i < 512) v = rdf(bq, i, isf);
      else if (i < 1024) v = rdf(bk, i - 512, isf);
      else if (i < 1536) v = rdf(bv, i - 1024, isf);
      else if (i < 2048) v = rdf(bo, i - 1536, isf);
      else if (i < 4096) v = rdf(b1, i - 2048, isf);
      else v = rdf(b2, i - 4096, isf);
      bcat[i] = v;
    }
    return;
  }
  const void* W;
  unsigned short* Wt;
  int K, N, t;
  if (bid < 1024) {
    K = 512; N = 512; t = bid & 255;
    if (bid < 256) { W = wq; Wt = wqkvT; }
    else if (bid < 512) { W = wk; Wt = wqkvT + 262144; }
    else if (bid < 768) { W = wv; Wt = wqkvT + 524288; }
    else { W = wo; Wt = woT; }
  } else if (bid < 2048) {
    W = w1; Wt = w1T; K = 512; N = 2048; t = bid - 1024;
  } else {
    W = w2; Wt = w2T; K = 2048; N = 512; t = bid - 2048;
  }
  int nx = N >> 5;
  int n0 = (t % nx) * 32, k0 = (t / nx) * 32;
#pragma unroll
  for (int i = 0; i < 4; i++) {
    int e = tid + i * 256;
    int r = e >> 5, c = e & 31;
    tile[r][c] = f2bf(rdf(W, (size_t)(k0 + r) * N + n0 + c, isf));
  }
  __syncthreads();
#pragma unroll
  for (int i = 0; i < 4; i++) {
    int e = tid + i * 256;
    int r = e >> 5, c = e & 31;
    Wt[(size_t)(n0 + r) * K + k0 + c] = tile[c][r];
  }
}

// ---------------- V transpose: qkb v-cols -> vbt[bh][d][s] --------------
__global__ __launch_bounds__(256) void vtrans_k(
    const unsigned short* __restrict__ qkb, unsigned short* __restrict__ vbt) {
  __shared__ unsigned short tile[32][33];
  int tid = threadIdx.x;
  int u = blockIdx.x;
  int s0 = (u & 63) * 32;
  int d0 = ((u >> 6) & 1) * 32;
  int bh = u >> 7, b = bh >> 3, h = bh & 7;
#pragma unroll
  for (int i = 0; i < 4; i++) {
    int e = tid + i * 256;
    int r = e >> 5, c = e & 31;
    tile[r][c] = qkb[((size_t)b * 2048 + s0 + r) * 1536 + 1024 + h * 64 + d0 + c];
  }
  __syncthreads();
#pragma unroll
  for (int i = 0; i < 4; i++) {
    int e = tid + i * 256;
    int r = e >> 5, c = e & 31;
    vbt[((size_t)bh * 64 + d0 + r) * 2048 + s0 + c] = tile[c][r];
  }
}

// ---------------- norm2 standalone (x1 f32 -> n2 bf16) ------------------
__global__ __launch_bounds__(256) void norm2_k(
    const void* __restrict__ xin, const void* __restrict__ alpha,
    const void* __restrict__ beta, unsigned short* __restrict__ out,
    const int* __restrict__ flag) {
  norm_unit<1>(xin, alpha, beta, out, flag[0], blockIdx.x);
}

// ---------------- GEMM: 128xTN tile, BK=64, XOR-swizzled LDS ------------
// QSC: scale columns n<512 by 0.18033688 (0.125*log2e) in f32 epilogue --
// folds attention's score scaling into Q exactly (bf16 rounding error is
// scale-invariant), so attn's softmax does exp2(pacc) with no multiply.
template <int TN, int RES, int OUTM, int RELU, int QSC>
__global__ __launch_bounds__(256, 3) void gemm2_k(
    const unsigned short* __restrict__ A,
    const unsigned short* __restrict__ Bt,
    const float* __restrict__ bias,
    const void* __restrict__ res,
    void* __restrict__ outp,
    int N, int K, const int* __restrict__ flag) {
  constexpr int MT = (TN == 128) ? 4 : 2;
  constexpr int BROWS = TN / 4;  // Bs rows staged per wave
  __shared__ alignas(16) unsigned short As[128 * 64];  // 16 KB
  __shared__ alignas(16) unsigned short Bs[TN * 64];   // 16/8 KB
  int isf = flag[0];
  int outf32 = (OUTM == 1) || (OUTM == 2 && isf);
  int tid = threadIdx.x;
  int wave = tid >> 6, lane = tid & 63;
  int quad = lane >> 4, l16 = lane & 15, l7 = l16 & 7;
  int wm = (TN == 128) ? (wave >> 1) : wave;
  int wn = (TN == 128) ? (wave & 1) : 0;
  size_t m0 = (size_t)blockIdx.x * 128;
  size_t n0 = (size_t)blockIdx.y * TN;

  int lrow = lane >> 3;                 // 0..7
  int gcol = 8 * ((lane & 7) ^ lrow);   // swizzled source chunk (shorts)

  const unsigned short* ag = A + (m0 + wave * 32 + lrow) * K + gcol;
  const unsigned short* bg = Bt + (n0 + wave * BROWS + lrow) * K + gcol;
  unsigned short* asl = &As[(wave * 32) * 64];
  unsigned short* bsl = &Bs[(wave * BROWS) * 64];

  f32x4 acc[MT][4];
#pragma unroll
  for (int i = 0; i < MT; i++)
#pragma unroll
    for (int j = 0; j < 4; j++) acc[i][j] = {0.f, 0.f, 0.f, 0.f};

  for (int k0 = 0; k0 < K; k0 += 64) {
    __syncthreads();
#pragma unroll
    for (int c = 0; c < 4; c++)
      gld16(ag + (size_t)(8 * c) * K + k0, asl + (8 * c) * 64);
#pragma unroll
    for (int c = 0; c < BROWS / 8; c++)
      gld16(bg + (size_t)(8 * c) * K + k0, bsl + (8 * c) * 64);
    __syncthreads();
#pragma unroll
    for (int ko = 0; ko < 2; ko++) {
      int slot = ((4 * ko + quad) ^ l7) * 8;
      bfrag af[MT], bf[4];
#pragma unroll
      for (int i = 0; i < MT; i++)
        af[i] = *(const bfrag*)&As[(wm * (MT * 16) + i * 16 + l16) * 64 + slot];
#pragma unroll
      for (int j = 0; j < 4; j++)
        bf[j] = *(const bfrag*)&Bs[(wn * 64 + j * 16 + l16) * 64 + slot];
#pragma unroll
      for (int i = 0; i < MT; i++)
#pragma unroll
        for (int j = 0; j < 4; j++)
          acc[i][j] = __builtin_amdgcn_mfma_f32_16x16x32_bf16(af[i], bf[j], acc[i][j], 0, 0, 0);
    }
  }
#pragma unroll
  for (int j = 0; j < 4; j++) {
    size_t n = n0 + wn * 64 + j * 16 + l16;
    float bv = bias[n];
#pragma unroll
    for (int i = 0; i < MT; i++) {
#pragma unroll
      for (int r = 0; r < 4; r++) {
        size_t m = m0 + wm * (MT * 16) + i * 16 + quad * 4 + r;
        float vv = acc[i][j][r] + bv;
        if (QSC && n < 512) vv *= 0.18033688f;
        if (RELU) vv = fmaxf(vv, 0.0f);
        if (RES == 1) vv += rdf(res, m * N + n, isf);
        else if (RES == 2) vv += ((const float*)res)[m * N + n];
        if (outf32) ((float*)outp)[m * N + n] = vv;
        else ((unsigned short*)outp)[m * N + n] = f2bf(vv);
      }
    }
  }
}

// ---------------- flash attention: 64q/wave, key-split, 8 waves ---------
// R6 lessons: staging/read halving worked (conflicts 4.19->2.10M); but
// launch_bounds(512,2)'s 128-reg allocation spilled ~20 regs around the
// BODY branch (WRITE_SIZE 18.9MB vs 8.2 output). This round: bounds(512)
// only -- the 8-wave block + 256-block grid already pin occupancy at
// 2 waves/SIMD, so the reg cap bought nothing. ~190 regs fit under the
// intrinsic 256 cap -> no spill. Q arrives pre-scaled by 0.125*log2e
// (folded into QKV gemm epilogue, exact in f32) -> softmax is exp2(pacc)
// directly: -64 v_mul/wave-iter and a shorter MFMA->exp chain.
__global__ __launch_bounds__(512) void attn_k(
    const unsigned short* __restrict__ qkb,  // [8192][1536] q|k|v (q scaled)
    const unsigned short* __restrict__ vbt,  // [32*64][2048] = V^T per bh
    const int* __restrict__ mask,
    unsigned short* __restrict__ ctx) {      // [8192][512]
  constexpr int S = 2048;
  __shared__ alignas(16) unsigned short Kt[2][2][64 * 64];  // [kh][buf] 32 KB
  __shared__ alignas(16) unsigned short Vt[2][2][64 * 64];  // [kh][buf] 32 KB
  __shared__ alignas(16) float mskf[S];                     // 8 KB
  __shared__ float ml[2][256];                              // 2 KB
  __shared__ int s_all;
  int tid = threadIdx.x, wave = tid >> 6, lane = tid & 63;
  int kh = wave >> 2, wv = wave & 3;
  int l32 = lane & 31, hi = lane >> 5;

  // XCD-aware work mapping (256 blocks, 8 XCDs round-robin by linear id)
  int lin = blockIdx.x;
  int work = (lin & 7) * 32 + (lin >> 3);
  int bh = work >> 3;          // 0..31 (4 consecutive bh per XCD)
  int q0 = (work & 7) * 256;   // 0..1792
  int b = bh >> 3, h = bh & 7;
  size_t rowbase = (size_t)b * S;

  // Q fragments (B-operand), 2 q-groups of 32: col=q=l32, k(d)=16ds+8hi+j
  bfrag qf[2][4];
#pragma unroll
  for (int qg = 0; qg < 2; qg++) {
    const unsigned short* qp =
        qkb + (rowbase + q0 + wv * 64 + qg * 32 + l32) * 1536 + h * 64 + hi * 8;
#pragma unroll
    for (int ds = 0; ds < 4; ds++) qf[qg][ds] = *(const bfrag*)(qp + ds * 16);
  }

  int srow_l = lane >> 3;  // 0..7; equals (staged row)&7 -> swizzle const/lane
  int sc = lane & 7;
  int swz = (sc ^ srow_l) * 8;
  const unsigned short* kgb = qkb + 512 + h * 64;
  const unsigned short* vgb = vbt + (size_t)bh * 64 * S;

  // staging pointers (strength-reduced); wave stages 16 rows of its half
  const unsigned short* kp[2];
  const unsigned short* vp[2];
#pragma unroll
  for (int i = 0; i < 2; i++) {
    int r = wv * 16 + i * 8 + srow_l;
    kp[i] = kgb + (rowbase + kh * 1024 + r) * 1536 + swz;
    vp[i] = vgb + (size_t)r * S + kh * 1024 + swz;
  }

  auto STAGE = [&](int buf) {
#pragma unroll
    for (int i = 0; i < 2; i++) {
      gld16(kp[i], &Kt[kh][buf][(wv * 16 + i * 8) * 64]);
      kp[i] += 64 * 1536;
      gld16(vp[i], &Vt[kh][buf][(wv * 16 + i * 8) * 64]);
      vp[i] += 64;
    }
  };

  f32x16 o[4];  // [qg*2+dt]
#pragma unroll
  for (int i = 0; i < 4; i++)
#pragma unroll
    for (int j = 0; j < 16; j++) o[i][j] = 0.f;
  float l_i[2] = {0.f, 0.f};

  STAGE(0);
  if (tid == 0) s_all = 1;
  __syncthreads();
  {
    int ok = 1;
    for (int i = tid; i < S; i += 512) {
      int mv = mask[rowbase + i];
      ok &= (mv != 0);
      mskf[i] = mv ? 0.0f : -1e5f;
    }
    atomicAnd(&s_all, ok);
  }
  __syncthreads();  // tile 0 + mask + s_all ready
  int am = s_all;

  auto BODY = [&](auto amc) {
    constexpr bool AM = decltype(amc)::value;
    for (int it = 0; it < 16; it++) {
      int cur = it & 1;
      if (it + 1 < 16) STAGE(cur ^ 1);  // in flight across whole compute

#pragma unroll
      for (int qg = 0; qg < 2; qg++) {
#pragma unroll
        for (int t = 0; t < 2; t++) {
          // ---- QK^T (swapped): pacc = D[key in sub-tile t][q] ----
          f32x16 pacc;
          {
            int r = t * 32 + l32;
            f32x16 z = {};
#pragma unroll
            for (int ds = 0; ds < 4; ds++) {
              int phys = ((2 * ds + hi) ^ (l32 & 7)) * 8;
              bfrag kf = *(const bfrag*)&Kt[kh][cur][r * 64 + phys];
              pacc = __builtin_amdgcn_mfma_f32_32x32x16_bf16(
                  kf, qf[qg][ds], ds == 0 ? z : pacc, 0, 0, 0);
            }
          }
          // ---- softmax (Q pre-scaled): key=(reg&3)+8*(reg>>2)+4*hi+32t --
          unsigned pb[8];
#pragma unroll
          for (int g = 0; g < 4; g++) {
            float p0, p1, p2, p3;
            if constexpr (AM) {
              p0 = __builtin_amdgcn_exp2f(pacc[g * 4 + 0]);
              p1 = __builtin_amdgcn_exp2f(pacc[g * 4 + 1]);
              p2 = __builtin_amdgcn_exp2f(pacc[g * 4 + 2]);
              p3 = __builtin_amdgcn_exp2f(pacc[g * 4 + 3]);
            } else {
              float4 m4 =
                  *(const float4*)&mskf[kh * 1024 + it * 64 + t * 32 + g * 8 + hi * 4];
              p0 = __builtin_amdgcn_exp2f(pacc[g * 4 + 0] + m4.x);
              p1 = __builtin_amdgcn_exp2f(pacc[g * 4 + 1] + m4.y);
              p2 = __builtin_amdgcn_exp2f(pacc[g * 4 + 2] + m4.z);
              p3 = __builtin_amdgcn_exp2f(pacc[g * 4 + 3] + m4.w);
            }
            l_i[qg] += (p0 + p1) + (p2 + p3);
            pb[g * 2] = cvtpk_bf16(p0, p1);
            pb[g * 2 + 1] = cvtpk_bf16(p2, p3);
          }
          // ---- PV for this sub-tile: ks = 2t+e ----
#pragma unroll
          for (int e = 0; e < 2; e++) {
            u32x2 sA = __builtin_amdgcn_permlane32_swap(
                pb[4 * e + 0], pb[4 * e + 2], false, false);
            u32x2 sB = __builtin_amdgcn_permlane32_swap(
                pb[4 * e + 1], pb[4 * e + 3], false, false);
            u32x4 pw = {sA.x, sB.x, sA.y, sB.y};
            bfrag pf = __builtin_bit_cast(bfrag, pw);
            int ks = 2 * t + e;
#pragma unroll
            for (int dt = 0; dt < 2; dt++) {
              int r = dt * 32 + l32;
              int phys = ((2 * ks + hi) ^ (l32 & 7)) * 8;
              bfrag vf = *(const bfrag*)&Vt[kh][cur][r * 64 + phys];
              o[qg * 2 + dt] = __builtin_amdgcn_mfma_f32_32x32x16_bf16(
                  pf, vf, o[qg * 2 + dt], 0, 0, 0);
            }
          }
        }
      }
      __syncthreads();  // next tile staged + all reads of cur done
    }
  };
  if (am) BODY(std::integral_constant<bool, true>{});
  else    BODY(std::integral_constant<bool, false>{});

  // ---- merge halves through LDS, normalize, store ----
#pragma unroll
  for (int qg = 0; qg < 2; qg++) {
    unsigned lu = __builtin_bit_cast(unsigned, l_i[qg]);
    u32x2 lr = __builtin_amdgcn_permlane32_swap(lu, lu, false, false);
    float l_tot = __builtin_bit_cast(float, lr.x) + __builtin_bit_cast(float, lr.y);
    if (lane < 32) ml[kh][wv * 64 + qg * 32 + l32] = l_tot;
  }
  float* mrgK = (float*)&Kt[0][0][0];  // 32 KB: 256q x 32d (dt=0), K dead
  float* mrgV = (float*)&Vt[0][0][0];  // 32 KB: 256q x 32d (dt=1), V dead
  if (kh == 1) {
#pragma unroll
    for (int qg = 0; qg < 2; qg++) {
#pragma unroll
      for (int reg = 0; reg < 16; reg++) {
        int ql = (reg & 3) + 8 * (reg >> 2) + 4 * hi;
        int qi = wv * 64 + qg * 32 + ql;
        mrgK[qi * 32 + l32] = o[qg * 2 + 0][reg];
        mrgV[qi * 32 + l32] = o[qg * 2 + 1][reg];
      }
    }
  }
  __syncthreads();
  if (kh == 0) {
#pragma unroll
    for (int qg = 0; qg < 2; qg++) {
#pragma unroll
      for (int reg = 0; reg < 16; reg++) {
        int ql = (reg & 3) + 8 * (reg >> 2) + 4 * hi;
        int qi = wv * 64 + qg * 32 + ql;
        float inv = 1.0f / fmaxf(ml[0][qi] + ml[1][qi], 1e-30f);
        size_t qrow = rowbase + q0 + qi;
        float v0 = (o[qg * 2 + 0][reg] + mrgK[qi * 32 + l32]) * inv;
        float v1 = (o[qg * 2 + 1][reg] + mrgV[qi * 32 + l32]) * inv;
        ctx[qrow * 512 + h * 64 + l32] = f2bf(v0);
        ctx[qrow * 512 + h * 64 + 32 + l32] = f2bf(v1);
      }
    }
  }
}

extern "C" void kernel_launch(void* const* d_in, const int* in_sizes, int n_in,
                              void* d_out, int out_size, void* d_ws, size_t ws_size,
                              hipStream_t stream) {
  const unsigned short* x = (const unsigned short*)d_in[0];
  const int* mask         = (const int*)d_in[1];
  const void* wq = d_in[2];  const void* bq = d_in[3];
  const void* wk = d_in[4];  const void* bk = d_in[5];
  const void* wv = d_in[6];  const void* bv = d_in[7];
  const void* wo = d_in[8];  const void* bo = d_in[9];
  const void* w1 = d_in[10]; const void* b1 = d_in[11];
  const void* w2 = d_in[12]; const void* b2 = d_in[13];
  const void* alpha1 = d_in[14]; const void* beta1 = d_in[15];
  const void* alpha2 = d_in[16]; const void* beta2 = d_in[17];

  char* ws = (char*)d_ws;
  int* flag            = (int*)(ws + 0);
  unsigned short* wqkvT= (unsigned short*)(ws + 65536);    // [1536][512]
  unsigned short* woT  = (unsigned short*)(ws + 1638400);
  unsigned short* w1T  = (unsigned short*)(ws + 2162688);  // [2048][512]
  unsigned short* w2T  = (unsigned short*)(ws + 4259840);  // [512][2048]
  float*          bcat = (float*)         (ws + 6356992);  // 4608 f32
  float*          x1   = (float*)         (ws + 6422528);  // [8192][512] f32
  unsigned short* n1   = (unsigned short*)(ws + 23199744); // also ctx, n2
  unsigned short* qkb  = (unsigned short*)(ws + 31588352); // [8192][1536]
  unsigned short* vbt  = (unsigned short*)(ws + 56754176); // [2048][2048]
  unsigned short* ff1  = qkb;                              // [8192][2048] overlay

  dim3 blk(256);

  setup_k<<<5138, blk, 0, stream>>>(x, wq, wk, wv, wo, w1, w2,
                                    wqkvT, woT, w1T, w2T,
                                    bq, bk, bv, bo, b1, b2, bcat,
                                    alpha1, beta1, n1, flag);
  // fused QKV (Q cols scaled by 0.125*log2e): [8192][512]@[1536][512]^T
  gemm2_k<128, 0, 0, 0, 1><<<dim3(64, 12), blk, 0, stream>>>(n1, wqkvT, bcat, nullptr, qkb, 1536, 512, flag);
  vtrans_k<<<4096, blk, 0, stream>>>(qkb, vbt);
  attn_k<<<256, dim3(512), 0, stream>>>(qkb, vbt, mask, n1);
  // out projection + residual(x) -> x1 f32
  gemm2_k<64, 1, 1, 0, 0><<<dim3(64, 8), blk, 0, stream>>>(n1, woT, bcat + 1536, (const void*)x, x1, 512, 512, flag);
  norm2_k<<<2048, blk, 0, stream>>>(x1, alpha2, beta2, n1, flag);
  // ffn1 + relu -> ff1
  gemm2_k<128, 0, 0, 1, 0><<<dim3(64, 16), blk, 0, stream>>>(n1, w1T, bcat + 2048, nullptr, ff1, 2048, 512, flag);
  // ffn2 + residual(x1) -> d_out
  gemm2_k<64, 2, 2, 0, 0><<<dim3(64, 8), blk, 0, stream>>>(ff1, w2T, bcat + 4096, x1, d_out, 512, 2048, flag);
}